// Round 2
// baseline (1229.553 us; speedup 1.0000x reference)
//
#include <hip/hip_runtime.h>

// FractalImage: B=16, 224x224, k = 3+2*kidx for kidx in [0,50), 3 metrics.
// One block per (kidx, b). Block = 256 threads = 4 waves.
// kidx<=7: thread-per-patch (P>=169, R<=8). kidx>=8: wave-per-patch (R<=20).
// Per-block LDS reduction, final fd/lac math in double on 3 threads.

__device__ __forceinline__ float wred64(float v) {
  #pragma unroll
  for (int off = 32; off > 0; off >>= 1) v += __shfl_xor(v, off, 64);
  return v;
}

__device__ __forceinline__ float sigm(float z) {
  return 1.0f / (1.0f + __expf(-z));   // sigmoid(z)
}

__global__ __launch_bounds__(256) void fractal_fused(const float* __restrict__ x,
                                                     float* __restrict__ out) {
  const int kidx = (int)blockIdx.x;
  const int b = (int)blockIdx.y;
  const int k = 3 + 2 * kidx;
  const int c = k >> 1;
  const int nw = 224 / k;
  const int P = nw * nw;
  const int k2 = k * k;
  int Rt = kidx + 1;                  // (k-1)/2 == kidx+1
  if (Rt < 2) Rt = 2;
  if (Rt > 20) Rt = 20;
  const int R = Rt;
  const float invk2 = 1.0f / (float)k2;
  const float* xb = x + b * 50176;

  const int tid = (int)threadIdx.x;
  const int wid = tid >> 6;
  const int lane = tid & 63;

  __shared__ float s_red[4][120];     // [wave][(m*20+r)*2 + {0:sum_n, 1:sum_n2}]

  if (kidx <= 7) {
    // ---------------- thread-per-patch path (k = 3..17, R <= 8) ----------------
    float sn[3][8], sn2[3][8];
    #pragma unroll
    for (int m = 0; m < 3; ++m)
      #pragma unroll
      for (int r = 0; r < 8; ++r) { sn[m][r] = 0.0f; sn2[m][r] = 0.0f; }

    for (int patch = tid; patch < P; patch += 256) {
      const int ph = patch / nw;
      const int pw = patch - ph * nw;
      const float* pb = xb + (ph * k) * 224 + pw * k;
      const float center = pb[c * 224 + c];

      float av[3][8];
      #pragma unroll
      for (int m = 0; m < 3; ++m)
        #pragma unroll
        for (int r = 0; r < 8; ++r) av[m][r] = 0.0f;

      for (int i = 0; i < k; ++i) {
        const int ady = (i >= c) ? (i - c) : (c - i);
        const float dy = (float)ady;
        const float* row = pb + i * 224;
        for (int j = 0; j < k; ++j) {
          const int adx = (j >= c) ? (j - c) : (c - j);
          const float dx = (float)adx;
          const float di = fabsf(row[j] - center);
          const float dch = fmaxf(fmaxf(dy, dx), di);
          const float deu = sqrtf(dy * dy + dx * dx + di * di);
          const float dma = dy + dx + di;
          #pragma unroll
          for (int r = 0; r < 8; ++r) {
            if (r < R) {
              const float rad = (float)(r + 1);
              av[0][r] += sigm((rad - dch) * 4.0f);
              av[1][r] += sigm((rad - deu) * 4.0f);
              av[2][r] += sigm((rad - dma) * 4.0f);
            }
          }
        }
      }
      #pragma unroll
      for (int m = 0; m < 3; ++m)
        #pragma unroll
        for (int r = 0; r < 8; ++r) {
          if (r < R) {
            const float n = av[m][r] * invk2;
            sn[m][r] += n;
            sn2[m][r] += n * n;
          }
        }
    }

    // wave-level butterfly reduce, lane 0 stores to LDS
    #pragma unroll
    for (int m = 0; m < 3; ++m)
      #pragma unroll
      for (int r = 0; r < 8; ++r) {
        if (r < R) {
          const float a = wred64(sn[m][r]);
          const float q = wred64(sn2[m][r]);
          if (lane == 0) {
            s_red[wid][(m * 20 + r) * 2] = a;
            s_red[wid][(m * 20 + r) * 2 + 1] = q;
          }
        }
      }
  } else {
    // ---------------- wave-per-patch path (k = 19..101, R = 9..20) ----------------
    float sn[3][20], sn2[3][20];
    #pragma unroll
    for (int m = 0; m < 3; ++m)
      #pragma unroll
      for (int r = 0; r < 20; ++r) { sn[m][r] = 0.0f; sn2[m][r] = 0.0f; }

    for (int patch = wid; patch < P; patch += 4) {
      const int ph = patch / nw;
      const int pw = patch - ph * nw;
      const float* pb = xb + (ph * k) * 224 + pw * k;
      const float center = pb[c * 224 + c];

      float av[3][20];
      #pragma unroll
      for (int m = 0; m < 3; ++m)
        #pragma unroll
        for (int r = 0; r < 20; ++r) av[m][r] = 0.0f;

      for (int p = lane; p < k2; p += 64) {
        const int i = p / k;
        const int j = p - i * k;
        const int ady = (i >= c) ? (i - c) : (c - i);
        const int adx = (j >= c) ? (j - c) : (c - j);
        const float dy = (float)ady;
        const float dx = (float)adx;
        const float di = fabsf(pb[i * 224 + j] - center);
        const float dch = fmaxf(fmaxf(dy, dx), di);
        const float deu = sqrtf(dy * dy + dx * dx + di * di);
        const float dma = dy + dx + di;
        #pragma unroll
        for (int r = 0; r < 20; ++r) {
          if (r < R) {
            const float rad = (float)(r + 1);
            av[0][r] += sigm((rad - dch) * 4.0f);
            av[1][r] += sigm((rad - deu) * 4.0f);
            av[2][r] += sigm((rad - dma) * 4.0f);
          }
        }
      }

      // per-patch reduction across the wave's 64 lanes
      #pragma unroll
      for (int m = 0; m < 3; ++m)
        #pragma unroll
        for (int r = 0; r < 20; ++r) {
          if (r < R) {
            const float tot = wred64(av[m][r]);
            if (lane == 0) {
              const float n = tot * invk2;
              sn[m][r] += n;
              sn2[m][r] += n * n;
            }
          }
        }
    }

    if (lane == 0) {
      #pragma unroll
      for (int m = 0; m < 3; ++m)
        #pragma unroll
        for (int r = 0; r < 20; ++r) {
          if (r < R) {
            s_red[wid][(m * 20 + r) * 2] = sn[m][r];
            s_red[wid][(m * 20 + r) * 2 + 1] = sn2[m][r];
          }
        }
    }
  }

  __syncthreads();

  // ---------------- final fd/lac math (double) on threads 0..2 ----------------
  if (tid < 3) {
    const int m = tid;
    const double invP = 1.0 / (double)P;

    double lx[20];
    double lsum = 0.0;
    #pragma unroll
    for (int r = 0; r < 20; ++r)
      if (r < R) { lx[r] = log((double)(r + 1)); lsum += lx[r]; }
    const double lmean = lsum / (double)R;
    double sxx = 0.0;
    #pragma unroll
    for (int r = 0; r < 20; ++r)
      if (r < R) { const double xc = lx[r] - lmean; sxx += xc * xc; }

    double sxy = 0.0, lacs = 0.0;
    #pragma unroll
    for (int r = 0; r < 20; ++r) {
      if (r < R) {
        const int idx = (m * 20 + r) * 2;
        const double m1 = ((double)s_red[0][idx] + (double)s_red[1][idx] +
                           (double)s_red[2][idx] + (double)s_red[3][idx]) * invP;
        const double m2 = ((double)s_red[0][idx + 1] + (double)s_red[1][idx + 1] +
                           (double)s_red[2][idx + 1] + (double)s_red[3][idx + 1]) * invP;
        lacs += m2 / (m1 * m1 + 1e-8);
        sxy += log(m1 + 1e-8) * (lx[r] - lmean);
      }
    }
    const double fd = -sxy / sxx;
    const double lac = lacs / (double)R;
    out[b * 300 + kidx * 3 + m] = (float)lac;          // cols 0..49: lacunarity
    out[b * 300 + (50 + kidx) * 3 + m] = (float)fd;    // cols 50..99: fractal dim
  }
}

extern "C" void kernel_launch(void* const* d_in, const int* in_sizes, int n_in,
                              void* d_out, int out_size, void* d_ws, size_t ws_size,
                              hipStream_t stream) {
  const float* x = (const float*)d_in[0];
  float* out = (float*)d_out;
  fractal_fused<<<dim3(50, 16), 256, 0, stream>>>(x, out);
}

// Round 3
// 356.521 us; speedup vs baseline: 3.4488x; 3.4488x over previous
//
#include <hip/hip_runtime.h>

// FractalImage: B=16, 224x224, k = 3+2*kidx, kidx in [0,50), 3 metrics.
// Chebyshev is data-independent (input in [0,1)) -> analytic in final kernel.
// Main kernel computes Euclid+Manhattan only, sigmoid via exp-recurrence:
//   E_r = e^{4(d-r)},  E_{r+1} = E_r * e^{-4},  sigma_r = rcp(1+E_r).
// Work-balanced chunks -> private ws partial slots (80 floats each), no atomics.

#define L2E4f 5.770780163555854f    // 4*log2(e)
#define QE4f  0.018315638888734f    // e^-4

struct Tabs {
  int gpre[51];      // prefix of chunks over scheduling sequence
  int CH[50];        // patches per chunk, indexed by kidx
  int kofseq[50];    // seq -> kidx (heavy blocks first)
  int GT;            // total chunks per batch image
};

__device__ __forceinline__ float wred64(float v) {
  #pragma unroll
  for (int off = 32; off > 0; off >>= 1) v += __shfl_xor(v, off, 64);
  return v;
}

__global__ __launch_bounds__(256) void fractal_main(const float* __restrict__ x,
                                                    float* __restrict__ ws, Tabs tab) {
  const int g = (int)blockIdx.x;
  const int b = (int)blockIdx.y;
  int seq = 0;
  while (g >= tab.gpre[seq + 1]) ++seq;     // uniform scalar scan
  const int kidx = tab.kofseq[seq];
  const int lc = g - tab.gpre[seq];
  const int k = 3 + 2 * kidx;
  const int c = k >> 1;
  const int nw = 224 / k;
  const int P = nw * nw;
  const int k2 = k * k;
  int R = kidx + 1; if (R < 2) R = 2; if (R > 20) R = 20;
  const float invk2 = 1.0f / (float)k2;
  const float* xb = x + b * 50176;
  const int tid = (int)threadIdx.x;
  const int wid = tid >> 6, lane = tid & 63;
  const int ch = tab.CH[kidx];
  const int pstart = lc * ch;
  int pend = pstart + ch; if (pend > P) pend = P;

  __shared__ float s_red[4][80];            // [wave][(m2*40) + r*2 + {sum_n,sum_n2}]
  for (int t = tid; t < 320; t += 256) (&s_red[0][0])[t] = 0.0f;
  __syncthreads();

  if (kidx <= 7) {
    // ---------------- thread-per-patch (k=3..17, R<=8, one chunk = all P) ----------------
    float sn[2][8], sn2[2][8];
    #pragma unroll
    for (int m = 0; m < 2; ++m)
      #pragma unroll
      for (int r = 0; r < 8; ++r) { sn[m][r] = 0.0f; sn2[m][r] = 0.0f; }

    for (int patch = pstart + tid; patch < pend; patch += 256) {
      const int ph = patch / nw, pw = patch - ph * nw;
      const float* pb = xb + (ph * k) * 224 + pw * k;
      const float center = pb[c * 224 + c];
      float av[2][8];
      #pragma unroll
      for (int m = 0; m < 2; ++m)
        #pragma unroll
        for (int r = 0; r < 8; ++r) av[m][r] = 0.0f;

      for (int i = 0; i < k; ++i) {
        const float dy = fabsf((float)(i - c));
        const float dy2 = dy * dy;
        const float* row = pb + i * 224;
        for (int j = 0; j < k; ++j) {
          const float dx = fabsf((float)(j - c));
          const float di = fabsf(row[j] - center);
          const float dman = dy + dx + di;
          const float deuc = sqrtf(dy2 + dx * dx + di * di);
          float Ee = __builtin_amdgcn_exp2f(L2E4f * (deuc - 1.0f));
          float Em = __builtin_amdgcn_exp2f(L2E4f * (dman - 1.0f));
          #pragma unroll
          for (int r = 0; r < 8; ++r) {
            if (r < R) {
              av[0][r] += __builtin_amdgcn_rcpf(1.0f + Ee);
              av[1][r] += __builtin_amdgcn_rcpf(1.0f + Em);
              Ee *= QE4f; Em *= QE4f;
            }
          }
        }
      }
      #pragma unroll
      for (int m = 0; m < 2; ++m)
        #pragma unroll
        for (int r = 0; r < 8; ++r) {
          if (r < R) {
            const float n = av[m][r] * invk2;
            sn[m][r] += n; sn2[m][r] += n * n;
          }
        }
    }
    #pragma unroll
    for (int m = 0; m < 2; ++m)
      #pragma unroll
      for (int r = 0; r < 8; ++r) {
        if (r < R) {
          const float a = wred64(sn[m][r]);
          const float q = wred64(sn2[m][r]);
          if (lane == 0) {
            s_red[wid][m * 40 + r * 2] = a;
            s_red[wid][m * 40 + r * 2 + 1] = q;
          }
        }
      }
  } else {
    // ---------------- wave-per-patch (k=19..101, R<=20) ----------------
    const float rcpk = 1.0f / (float)k;
    for (int patch = pstart + wid; patch < pend; patch += 4) {
      const int ph = patch / nw, pw = patch - ph * nw;
      const float* pb = xb + (ph * k) * 224 + pw * k;
      const float center = pb[c * 224 + c];
      float av[2][20];
      #pragma unroll
      for (int m = 0; m < 2; ++m)
        #pragma unroll
        for (int r = 0; r < 20; ++r) av[m][r] = 0.0f;

      for (int p = lane; p < k2; p += 64) {
        const int i = (int)(((float)p + 0.5f) * rcpk);   // exact for p<2^24, k<=101
        const int j = p - i * k;
        const float dy = fabsf((float)(i - c));
        const float dx = fabsf((float)(j - c));
        const float di = fabsf(pb[i * 224 + j] - center);
        const float dman = dy + dx + di;
        const float deuc = sqrtf(dy * dy + dx * dx + di * di);
        float Ee = __builtin_amdgcn_exp2f(L2E4f * (deuc - 1.0f));
        float Em = __builtin_amdgcn_exp2f(L2E4f * (dman - 1.0f));
        #pragma unroll
        for (int r = 0; r < 20; ++r) {
          if (r < R) {
            av[0][r] += __builtin_amdgcn_rcpf(1.0f + Ee);
            av[1][r] += __builtin_amdgcn_rcpf(1.0f + Em);
            Ee *= QE4f; Em *= QE4f;
          }
        }
      }
      #pragma unroll
      for (int m = 0; m < 2; ++m)
        #pragma unroll
        for (int r = 0; r < 20; ++r) {
          if (r < R) {
            const float tot = wred64(av[m][r]);
            if (lane == 0) {
              const float n = tot * invk2;
              s_red[wid][m * 40 + r * 2] += n;
              s_red[wid][m * 40 + r * 2 + 1] += n * n;
            }
          }
        }
    }
  }

  __syncthreads();
  float* dst = ws + ((size_t)b * tab.GT + g) * 80;
  if (tid < 80) dst[tid] = s_red[0][tid] + s_red[1][tid] + s_red[2][tid] + s_red[3][tid];
}

__global__ __launch_bounds__(64) void fractal_final(const float* __restrict__ ws,
                                                    float* __restrict__ out, Tabs tab) {
  const int t = (int)(blockIdx.x * 64 + threadIdx.x);
  if (t >= 800) return;
  const int kidx = t / 16, b = t - (t / 16) * 16;
  int seq = 0;
  for (int j = 0; j < 50; ++j) if (tab.kofseq[j] == kidx) seq = j;
  const int g0 = tab.gpre[seq], g1 = tab.gpre[seq + 1];
  const int k = 3 + 2 * kidx, c = k >> 1, nw = 224 / k;
  const int P = nw * nw, k2 = k * k;
  int R = kidx + 1; if (R < 2) R = 2; if (R > 20) R = 20;
  const double invP = 1.0 / (double)P;

  double lx[20], lsum = 0.0;
  #pragma unroll
  for (int r = 0; r < 20; ++r)
    if (r < R) { lx[r] = log((double)(r + 1)); lsum += lx[r]; }
  const double lmean = lsum / (double)R;
  double sxx = 0.0;
  #pragma unroll
  for (int r = 0; r < 20; ++r)
    if (r < R) { const double xc = lx[r] - lmean; sxx += xc * xc; }

  for (int m = 0; m < 3; ++m) {
    double sxy = 0.0, lacs = 0.0;
    for (int r = 0; r < 20; ++r) {
      if (r < R) {
        double m1, m2;
        if (m == 0) {
          // analytic Chebyshev: center d=0 (di==0 always), ring s has 8s pixels, d=s
          float acc = 1.0f / (1.0f + __expf(-4.0f * (float)(r + 1)));
          for (int s = 1; s <= c; ++s)
            acc += 8.0f * (float)s / (1.0f + __expf(-4.0f * (float)(r + 1 - s)));
          m1 = (double)acc / (double)k2;
          m2 = m1 * m1;
        } else {
          double sn = 0.0, sn2 = 0.0;
          for (int g = g0; g < g1; ++g) {
            const float* p = ws + ((size_t)b * tab.GT + g) * 80 + (m - 1) * 40 + r * 2;
            sn += (double)p[0]; sn2 += (double)p[1];
          }
          m1 = sn * invP; m2 = sn2 * invP;
        }
        lacs += m2 / (m1 * m1 + 1e-8);
        sxy += log(m1 + 1e-8) * (lx[r] - lmean);
      }
    }
    out[b * 300 + kidx * 3 + m] = (float)(lacs / (double)R);          // cols 0..49: lac
    out[b * 300 + (50 + kidx) * 3 + m] = (float)(-sxy / sxx);         // cols 50..99: fd
  }
}

extern "C" void kernel_launch(void* const* d_in, const int* in_sizes, int n_in,
                              void* d_out, int out_size, void* d_ws, size_t ws_size,
                              hipStream_t stream) {
  Tabs tab;
  int G_[50]; long wblk[50];
  for (int i = 0; i < 50; ++i) {
    const int k = 3 + 2 * i, nw = 224 / k, P = nw * nw;
    int R = i + 1; if (R < 2) R = 2; if (R > 20) R = 20;
    const long w = (long)k * k * (2 + R);        // per-patch cost weight
    const long W = (long)P * w;                  // per-(kidx,b) cost
    int G = (int)((W + 325999) / 326000);        // ~326k-weight chunks
    if (G < 1) G = 1;
    if (G > P) G = P;
    if (i <= 7) G = 1;                            // thread-per-patch path: one chunk
    if (P <= 4) G = 1;                            // keep all 4 waves busy
    int ch = (P + G - 1) / G;
    G = (P + ch - 1) / ch;
    G_[i] = G; tab.CH[i] = ch;
    wblk[i] = W / G;                              // per-block weight (for scheduling order)
  }
  // schedule heaviest blocks first (dispatch roughly follows blockIdx.x)
  int ord[50];
  for (int i = 0; i < 50; ++i) ord[i] = i;
  for (int a = 1; a < 50; ++a) {
    const int key = ord[a]; const long kw = wblk[key];
    int bp = a - 1;
    while (bp >= 0 && wblk[ord[bp]] < kw) { ord[bp + 1] = ord[bp]; --bp; }
    ord[bp + 1] = key;
  }
  tab.gpre[0] = 0;
  for (int j = 0; j < 50; ++j) {
    tab.kofseq[j] = ord[j];
    tab.gpre[j + 1] = tab.gpre[j] + G_[ord[j]];
  }
  tab.GT = tab.gpre[50];

  const float* x = (const float*)d_in[0];
  float* out = (float*)d_out;
  float* wsf = (float*)d_ws;   // 16 * GT * 80 floats (~0.6 MB), fully rewritten each launch

  fractal_main<<<dim3(tab.GT, 16), 256, 0, stream>>>(x, wsf, tab);
  fractal_final<<<13, 64, 0, stream>>>(wsf, out, tab);
}

// Round 4
// 266.027 us; speedup vs baseline: 4.6219x; 1.3402x over previous
//
#include <hip/hip_runtime.h>

// FractalImage: B=16, 224x224, k = 3+2*kidx, kidx in [0,50), 3 metrics.
// Chebyshev is data-independent (x in [0,1)) -> analytic in finalize.
// Main kernel: Euclid+Manhattan, sigmoid via exp recurrence
//   E_r = e^{4(d-r)}, E_{r+1} = E_r*e^{-4}, sigma_r = rcp(1+E_r).
// Subwave-per-patch: LP lanes per patch (LP=1/4/16/64 by k), 256/LP patches
// concurrent per block; k>=45 uses block-per-patch. Host chunker targets
// ~10k wave-cycles per block from an explicit cycle model, heavy-first.

#define L2E4f 5.770780163555854f    // 4*log2(e)
#define QE4f  0.018315638888734f    // e^-4

struct Tabs {
  int gpre[51];      // chunk-count prefix over scheduling sequence
  int CH[50];        // patches per chunk, by kidx
  int kofseq[50];    // seq -> kidx (heaviest blocks first)
  int GT;            // total chunks per image
};

__device__ __forceinline__ float wred64(float v) {
#pragma unroll
  for (int off = 32; off > 0; off >>= 1) v += __shfl_xor(v, off, 64);
  return v;
}

// Generic subwave path: LP = 1<<lpl lanes cooperate on one patch; a block
// processes 256>>lpl patches concurrently. Per round: group-reduce patch sums,
// cross-group reduce n and n^2, lane 0 accumulates into s_red[wid].
template<int MAXR>
__device__ __forceinline__ void subwave_path(
    const float* __restrict__ xb, float (*s_red)[80],
    int k, int c, int nw, int k2, int R, float invk2, float rcpk,
    int pstart, int pend, int ch, int lpl, int wid, int lane) {
  const int LP = 1 << lpl;
  const int grp = lane >> lpl;
  const int l0 = lane & (LP - 1);
  const int gpw = 64 >> lpl;          // groups (patches) per wave
  const int conc = gpw << 2;          // patches per block-round
  const int rounds = (ch + conc - 1) / conc;

  for (int it = 0; it < rounds; ++it) {
    const int patch = pstart + it * conc + wid * gpw + grp;
    float av[2][MAXR];
#pragma unroll
    for (int m = 0; m < 2; ++m)
#pragma unroll
      for (int r = 0; r < MAXR; ++r) av[m][r] = 0.0f;

    if (patch < pend) {
      const int ph = patch / nw, pw = patch - ph * nw;
      const float* pb = xb + (ph * k) * 224 + pw * k;
      const float center = pb[c * 224 + c];
      for (int p = l0; p < k2; p += LP) {
        const int i = (int)(((float)p + 0.5f) * rcpk);   // exact floor(p/k)
        const int j = p - i * k;
        const float dy = fabsf((float)(i - c));
        const float dx = fabsf((float)(j - c));
        const float di = fabsf(pb[i * 224 + j] - center);
        const float dman = dy + dx + di;
        const float deuc = sqrtf(dy * dy + dx * dx + di * di);
        float Ee = __builtin_amdgcn_exp2f(L2E4f * (deuc - 1.0f));
        float Em = __builtin_amdgcn_exp2f(L2E4f * (dman - 1.0f));
#pragma unroll
        for (int r = 0; r < MAXR; ++r) {
          if (r < R) {
            av[0][r] += __builtin_amdgcn_rcpf(1.0f + Ee);
            av[1][r] += __builtin_amdgcn_rcpf(1.0f + Em);
            Ee *= QE4f; Em *= QE4f;
          }
        }
      }
    }
    // reduce: within-group total -> per-patch n, n^2 -> cross-group wave sum
#pragma unroll
    for (int m = 0; m < 2; ++m)
#pragma unroll
      for (int r = 0; r < MAXR; ++r) {
        if (r < R) {
          float t = av[m][r];
          for (int off = LP >> 1; off > 0; off >>= 1) t += __shfl_xor(t, off, 64);
          float n = t * invk2;
          float nn = n * n;
          for (int off = LP; off < 64; off <<= 1) {
            n += __shfl_xor(n, off, 64);
            nn += __shfl_xor(nn, off, 64);
          }
          if (lane == 0) {
            s_red[wid][m * 40 + r * 2] += n;
            s_red[wid][m * 40 + r * 2 + 1] += nn;
          }
        }
      }
  }
}

__global__ __launch_bounds__(256) void fractal_main(const float* __restrict__ x,
                                                    float* __restrict__ ws, Tabs tab) {
  const int g = (int)blockIdx.x;
  const int b = (int)blockIdx.y;
  int seq = 0;
  while (g >= tab.gpre[seq + 1]) ++seq;      // uniform scalar scan
  const int kidx = tab.kofseq[seq];
  const int lc = g - tab.gpre[seq];
  const int k = 3 + 2 * kidx, c = k >> 1, nw = 224 / k;
  const int P = nw * nw, k2 = k * k;
  int R = kidx + 1; if (R < 2) R = 2; if (R > 20) R = 20;
  const float invk2 = 1.0f / (float)k2;
  const float rcpk = 1.0f / (float)k;
  const float* xb = x + b * 50176;
  const int tid = (int)threadIdx.x, wid = tid >> 6, lane = tid & 63;
  const int ch = tab.CH[kidx];
  const int pstart = lc * ch;
  int pend = pstart + ch; if (pend > P) pend = P;

  __shared__ float s_red[4][80];
  __shared__ float s_acc[80];
  for (int t = tid; t < 320; t += 256) (&s_red[0][0])[t] = 0.0f;
  if (tid < 80) s_acc[tid] = 0.0f;
  __syncthreads();

  if (kidx <= 20) {
    int lpl;
    if (kidx <= 2) lpl = 0;          // k=3..7: thread-per-patch
    else if (kidx <= 6) lpl = 2;     // k=9..15: 4 lanes/patch
    else if (kidx <= 12) lpl = 4;    // k=17..27: 16 lanes/patch
    else lpl = 6;                    // k=29..43: wave/patch
    if (kidx <= 6)
      subwave_path<8>(xb, s_red, k, c, nw, k2, R, invk2, rcpk, pstart, pend, ch, lpl, wid, lane);
    else
      subwave_path<20>(xb, s_red, k, c, nw, k2, R, invk2, rcpk, pstart, pend, ch, lpl, wid, lane);
    __syncthreads();
    float* dst = ws + ((size_t)b * tab.GT + g) * 80;
    if (tid < 80) dst[tid] = s_red[0][tid] + s_red[1][tid] + s_red[2][tid] + s_red[3][tid];
  } else {
    // ---------------- block-per-patch (k>=45): 256 lanes stripe one patch ----------------
    for (int patch = pstart; patch < pend; ++patch) {
      const int ph = patch / nw, pw = patch - ph * nw;
      const float* pb = xb + (ph * k) * 224 + pw * k;
      const float center = pb[c * 224 + c];
      float av[2][20];
#pragma unroll
      for (int m = 0; m < 2; ++m)
#pragma unroll
        for (int r = 0; r < 20; ++r) av[m][r] = 0.0f;

      for (int p = tid; p < k2; p += 256) {
        const int i = (int)(((float)p + 0.5f) * rcpk);
        const int j = p - i * k;
        const float dy = fabsf((float)(i - c));
        const float dx = fabsf((float)(j - c));
        const float di = fabsf(pb[i * 224 + j] - center);
        const float dman = dy + dx + di;
        const float deuc = sqrtf(dy * dy + dx * dx + di * di);
        float Ee = __builtin_amdgcn_exp2f(L2E4f * (deuc - 1.0f));
        float Em = __builtin_amdgcn_exp2f(L2E4f * (dman - 1.0f));
#pragma unroll
        for (int r = 0; r < 20; ++r) {
          if (r < R) {
            av[0][r] += __builtin_amdgcn_rcpf(1.0f + Ee);
            av[1][r] += __builtin_amdgcn_rcpf(1.0f + Em);
            Ee *= QE4f; Em *= QE4f;
          }
        }
      }
#pragma unroll
      for (int m = 0; m < 2; ++m)
#pragma unroll
        for (int r = 0; r < 20; ++r) {
          if (r < R) {
            const float t = wred64(av[m][r]);
            if (lane == 0) s_red[wid][m * 20 + r] = t;
          }
        }
      __syncthreads();
      if (tid < 40) {
        const int m = tid / 20, r = tid - 20 * (tid / 20);
        if (r < R) {
          const float tot = s_red[0][m * 20 + r] + s_red[1][m * 20 + r] +
                            s_red[2][m * 20 + r] + s_red[3][m * 20 + r];
          const float n = tot * invk2;
          s_acc[m * 40 + r * 2] += n;
          s_acc[m * 40 + r * 2 + 1] += n * n;
        }
      }
      __syncthreads();
    }
    float* dst = ws + ((size_t)b * tab.GT + g) * 80;
    if (tid < 80) dst[tid] = s_acc[tid];
  }
}

__global__ __launch_bounds__(256) void fractal_final(const float* __restrict__ ws,
                                                     float* __restrict__ out, Tabs tab) {
  const int t = (int)(blockIdx.x * 256 + threadIdx.x);
  if (t >= 2400) return;
  const int kidx = t / 48;
  const int rem = t - kidx * 48;
  const int b = rem / 3;
  const int m = rem - b * 3;
  int seq = 0;
  for (int j = 0; j < 50; ++j) if (tab.kofseq[j] == kidx) seq = j;
  const int g0 = tab.gpre[seq], g1 = tab.gpre[seq + 1];
  const int k = 3 + 2 * kidx, c = k >> 1, nw = 224 / k;
  const int P = nw * nw, k2 = k * k;
  int R = kidx + 1; if (R < 2) R = 2; if (R > 20) R = 20;
  const float invP = 1.0f / (float)P;
  const float invk2 = 1.0f / (float)k2;

  float lx[20], lsum = 0.0f;
#pragma unroll
  for (int r = 0; r < 20; ++r)
    if (r < R) { lx[r] = logf((float)(r + 1)); lsum += lx[r]; }
  const float lmean = lsum / (float)R;
  float sxx = 0.0f;
#pragma unroll
  for (int r = 0; r < 20; ++r)
    if (r < R) { const float xc = lx[r] - lmean; sxx += xc * xc; }

  float sxy = 0.0f, lacs = 0.0f;
  for (int r = 0; r < 20; ++r) {
    if (r < R) {
      float m1, m2;
      if (m == 0) {
        // analytic Chebyshev: d = ring index s exactly; rings s<=r-2 saturated
        int s0 = r - 2; if (s0 > c) s0 = c;
        float acc = (s0 >= 0) ? (1.0f + 4.0f * (float)s0 * (float)(s0 + 1)) : 0.0f;
        int slo = r - 1; if (slo < 0) slo = 0;
        int shi = r + 4; if (shi > c) shi = c;
        for (int s = slo; s <= shi; ++s) {
          const float w = (s == 0) ? 1.0f : 8.0f * (float)s;
          acc += w / (1.0f + __expf(4.0f * (float)(s - r - 1)));
        }
        m1 = acc * invk2;
        m2 = m1 * m1;
      } else {
        float sn = 0.0f, sn2 = 0.0f;
        for (int gg = g0; gg < g1; ++gg) {
          const float* p = ws + ((size_t)b * tab.GT + gg) * 80 + (m - 1) * 40 + r * 2;
          sn += p[0]; sn2 += p[1];
        }
        m1 = sn * invP; m2 = sn2 * invP;
      }
      lacs += m2 / (m1 * m1 + 1e-8f);
      sxy += logf(m1 + 1e-8f) * (lx[r] - lmean);
    }
  }
  out[b * 300 + kidx * 3 + m] = lacs / (float)R;           // cols 0..49: lacunarity
  out[b * 300 + (50 + kidx) * 3 + m] = -sxy / sxx;         // cols 50..99: fractal dim
}

extern "C" void kernel_launch(void* const* d_in, const int* in_sizes, int n_in,
                              void* d_out, int out_size, void* d_ws, size_t ws_size,
                              hipStream_t stream) {
  Tabs tab;
  long T = 10000;                       // target wave-cycles per block
  int G_[50], CH_[50];
  long bc[50];
  for (int tries = 0; tries < 8; ++tries) {
    long GTl = 0;
    for (int i = 0; i < 50; ++i) {
      const int k = 3 + 2 * i, nw = 224 / k, P = nw * nw, k2 = k * k;
      int R = i + 1; if (R < 2) R = 2; if (R > 20) R = 20;
      const int lpl = (i <= 2) ? 0 : (i <= 6) ? 2 : (i <= 12) ? 4 : (i <= 20) ? 6 : 8;
      const int LP = 1 << lpl;
      const int conc = (lpl == 8) ? 1 : (256 >> lpl);
      const long rc = (long)((k2 + LP - 1) / LP) * 2L * (12L * R + 8L);  // cycles per round
      long np = T / rc; if (np < 1) np = 1;
      long cht = np * conc; if (cht > P) cht = P;
      int G = (int)(((long)P + cht - 1) / cht);
      int ch = (P + G - 1) / G;
      G = (P + ch - 1) / ch;
      G_[i] = G; CH_[i] = ch;
      bc[i] = (long)((ch + conc - 1) / conc) * rc;
      GTl += G;
    }
    if (16L * GTl * 80L * 4L <= (long)ws_size || tries == 7) break;
    T *= 2;
  }
  // heaviest blocks first
  int ord[50];
  for (int i = 0; i < 50; ++i) ord[i] = i;
  for (int a = 1; a < 50; ++a) {
    const int key = ord[a]; const long kw = bc[key];
    int bp = a - 1;
    while (bp >= 0 && bc[ord[bp]] < kw) { ord[bp + 1] = ord[bp]; --bp; }
    ord[bp + 1] = key;
  }
  tab.gpre[0] = 0;
  for (int j = 0; j < 50; ++j) {
    tab.kofseq[j] = ord[j];
    tab.gpre[j + 1] = tab.gpre[j] + G_[ord[j]];
  }
  for (int i = 0; i < 50; ++i) tab.CH[i] = CH_[i];
  tab.GT = tab.gpre[50];

  const float* x = (const float*)d_in[0];
  fractal_main<<<dim3(tab.GT, 16), 256, 0, stream>>>(x, (float*)d_ws, tab);
  fractal_final<<<10, 256, 0, stream>>>((const float*)d_ws, (float*)d_out, tab);
}